// Round 1
// baseline (384.580 us; speedup 1.0000x reference)
//
#include <hip/hip_runtime.h>

typedef __attribute__((ext_vector_type(8))) __bf16 bf16x8;
typedef __attribute__((ext_vector_type(4))) float f32x4;

#define BSZ 4
#define CCH 512
#define SEQ 2048
#define NH  8
#define HD  64
// C*S = 2^20 per batch

__device__ __forceinline__ f32x4 mfma16(bf16x8 a, bf16x8 b, f32x4 c) {
  return __builtin_amdgcn_mfma_f32_16x16x32_bf16(a, b, c, 0, 0, 0);
}

__device__ __forceinline__ void gload16(const void* g, void* l) {
  __builtin_amdgcn_global_load_lds((const __attribute__((address_space(1))) void*)g,
                                   (__attribute__((address_space(3))) void*)l,
                                   16, 0, 0);
}

// ---------------- GroupNorm reduction ----------------
__global__ __launch_bounds__(256) void gn_partial(const float* __restrict__ x,
                                                  float* __restrict__ stats) {
  int b = blockIdx.y;
  const float4* xb = (const float4*)(x + ((size_t)b << 20) + (size_t)blockIdx.x * 16384);
  int tid = threadIdx.x;
  float s = 0.f, sq = 0.f;
#pragma unroll
  for (int i = 0; i < 16; ++i) {
    float4 v = xb[i * 256 + tid];
    s  += v.x + v.y + v.z + v.w;
    sq += v.x * v.x + v.y * v.y + v.z * v.z + v.w * v.w;
  }
#pragma unroll
  for (int o = 32; o > 0; o >>= 1) { s += __shfl_down(s, o); sq += __shfl_down(sq, o); }
  __shared__ float ls[4], lq[4];
  int w = tid >> 6;
  if ((tid & 63) == 0) { ls[w] = s; lq[w] = sq; }
  __syncthreads();
  if (tid == 0) {
    float S = ls[0] + ls[1] + ls[2] + ls[3];
    float Q = lq[0] + lq[1] + lq[2] + lq[3];
    atomicAdd(&stats[b], S);
    atomicAdd(&stats[4 + b], Q);
  }
}

__global__ void gn_final(float* stats) {
  int t = threadIdx.x;
  if (t < 4) {
    const float n = 1048576.f;
    float mean = stats[t] / n;
    float var = stats[4 + t] / n - mean * mean;
    stats[8 + t]  = mean;
    stats[12 + t] = rsqrtf(var + 1e-5f);
  }
}

// ---------------- normalize + transpose to [B*S, C] bf16 ----------------
__global__ __launch_bounds__(256) void norm_tr(const float* __restrict__ x,
                                               const float* __restrict__ gw,
                                               const float* __restrict__ gb,
                                               const float* __restrict__ stats,
                                               __bf16* __restrict__ h) {
  int s0 = blockIdx.x * 64, c0 = blockIdx.y * 64, b = blockIdx.z;
  float mean = stats[8 + b], rstd = stats[12 + b];
  const float* xb = x + ((size_t)b << 20);
  __shared__ __align__(16) __bf16 tile[64][72];
  int tid = threadIdx.x;
#pragma unroll
  for (int j = 0; j < 16; ++j) {
    int e = tid + j * 256;
    int cl = e >> 6, sl = e & 63;
    float vv = xb[(size_t)(c0 + cl) * 2048 + s0 + sl];
    float hn = (vv - mean) * rstd * gw[c0 + cl] + gb[c0 + cl];
    tile[cl][sl] = (__bf16)hn;
  }
  __syncthreads();
#pragma unroll
  for (int j = 0; j < 2; ++j) {
    int row = (tid >> 3) + j * 32;  // s-local
    int cg = tid & 7;
    bf16x8 pk;
#pragma unroll
    for (int e = 0; e < 8; ++e) pk[e] = tile[cg * 8 + e][row];
    *(bf16x8*)&h[(size_t)((b << 11) + s0 + row) * 512 + c0 + cg * 8] = pk;
  }
}

// ---------------- weights fp32 -> bf16 ----------------
__global__ __launch_bounds__(256) void wcvt(const float* __restrict__ wq, const float* __restrict__ wk,
                                            const float* __restrict__ wv, const float* __restrict__ wo,
                                            __bf16* __restrict__ out) {
  int i = blockIdx.x * 256 + threadIdx.x;  // 0..262143
  out[i]          = (__bf16)wq[i];
  out[262144 + i] = (__bf16)wk[i];
  out[524288 + i] = (__bf16)wv[i];
  out[786432 + i] = (__bf16)wo[i];
}

// ---------------- QKV GEMM: [8192,512] x [512,512]^T ----------------
__global__ __launch_bounds__(256) void gemm_qkv(const __bf16* __restrict__ A, const __bf16* __restrict__ Wb,
                                                const float* __restrict__ bq, const float* __restrict__ bk,
                                                const float* __restrict__ bvv,
                                                __bf16* __restrict__ oq, __bf16* __restrict__ ok,
                                                __bf16* __restrict__ ov) {
  __shared__ __align__(16) __bf16 As[128 * 64];
  __shared__ __align__(16) __bf16 Bs[128 * 64];
  int z = blockIdx.z;
  const __bf16* W = Wb + (size_t)z * 262144;
  const float* bias = z == 0 ? bq : (z == 1 ? bk : bvv);
  __bf16* out = z == 0 ? oq : (z == 1 ? ok : ov);
  int tid = threadIdx.x, wid = tid >> 6, l = tid & 63;
  int m0 = blockIdx.x * 128, n0 = blockIdx.y * 128;
  int wm = (wid >> 1) * 64, wn = (wid & 1) * 64;
  int l16 = l & 15, lg = l >> 4;
  f32x4 zero = {0.f, 0.f, 0.f, 0.f};
  f32x4 acc[4][4];
#pragma unroll
  for (int mt = 0; mt < 4; ++mt)
#pragma unroll
    for (int nt = 0; nt < 4; ++nt) acc[mt][nt] = zero;
  int srow = wid * 32 + (l >> 3);
  int scol = (l & 7) * 8;
  for (int k0 = 0; k0 < 512; k0 += 64) {
    __syncthreads();
#pragma unroll
    for (int t = 0; t < 4; ++t) {
      gload16(A + (size_t)(m0 + srow + t * 8) * 512 + k0 + scol, &As[(wid * 32 + t * 8) * 64]);
      gload16(W + (size_t)(n0 + srow + t * 8) * 512 + k0 + scol, &Bs[(wid * 32 + t * 8) * 64]);
    }
    __syncthreads();
#pragma unroll
    for (int kk = 0; kk < 64; kk += 32) {
      bf16x8 af[4], bfr[4];
#pragma unroll
      for (int mt = 0; mt < 4; ++mt) af[mt] = *(const bf16x8*)&As[(wm + mt * 16 + l16) * 64 + kk + lg * 8];
#pragma unroll
      for (int nt = 0; nt < 4; ++nt) bfr[nt] = *(const bf16x8*)&Bs[(wn + nt * 16 + l16) * 64 + kk + lg * 8];
#pragma unroll
      for (int mt = 0; mt < 4; ++mt)
#pragma unroll
        for (int nt = 0; nt < 4; ++nt) acc[mt][nt] = mfma16(af[mt], bfr[nt], acc[mt][nt]);
    }
  }
#pragma unroll
  for (int nt = 0; nt < 4; ++nt) {
    int col = n0 + wn + nt * 16 + l16;
    float bb = bias[col];
#pragma unroll
    for (int mt = 0; mt < 4; ++mt)
#pragma unroll
      for (int r = 0; r < 4; ++r)
        out[(size_t)(m0 + wm + mt * 16 + lg * 4 + r) * 512 + col] = (__bf16)(acc[mt][nt][r] + bb);
  }
}

// ---------------- V transpose -> V^T [B,H,D,S] ----------------
__global__ __launch_bounds__(256) void v_tr(const __bf16* __restrict__ v, __bf16* __restrict__ vt) {
  int s0 = blockIdx.x * 64, hh = blockIdx.y, b = blockIdx.z;
  __shared__ __align__(16) __bf16 tile[64][72];  // [d][s]
  int tid = threadIdx.x;
#pragma unroll
  for (int j = 0; j < 16; ++j) {
    int e = tid + j * 256;  // 0..4095
    int sl = e >> 6, dl = e & 63;
    tile[dl][sl] = v[(size_t)((b << 11) + s0 + sl) * 512 + hh * 64 + dl];
  }
  __syncthreads();
  const size_t base = (size_t)((b * 8 + hh) * 64) * 2048;
#pragma unroll
  for (int j = 0; j < 2; ++j) {
    int d = tid >> 2;             // 0..63
    int ch = (tid & 3) + j * 4;   // 0..7
    bf16x8 pk = *(const bf16x8*)&tile[d][ch * 8];
    *(bf16x8*)&vt[base + (size_t)d * 2048 + s0 + ch * 8] = pk;
  }
}

// ---------------- flash attention ----------------
__global__ __launch_bounds__(256) void attn(const __bf16* __restrict__ q, const __bf16* __restrict__ k,
                                            const __bf16* __restrict__ vt, __bf16* __restrict__ ao) {
  int tid = threadIdx.x, w = tid >> 6, l = tid & 63;
  int s0 = blockIdx.x * 64 + w * 16;  // wave's q-row base within batch
  int hh = blockIdx.y, b = blockIdx.z;
  int l16 = l & 15, lg = l >> 4;

  const __bf16* qrow = q + ((size_t)((b << 11) + s0 + l16)) * 512 + hh * 64;
  bf16x8 qf0 = *(const bf16x8*)&qrow[lg * 8];
  bf16x8 qf1 = *(const bf16x8*)&qrow[32 + lg * 8];

  const __bf16* kbase = k + ((size_t)(b << 11)) * 512 + hh * 64;
  const __bf16* vtb = vt + ((size_t)((b * 8 + hh) * 64)) * 2048;

  __shared__ __align__(16) __bf16 lp[4][16][72];

  f32x4 zero = {0.f, 0.f, 0.f, 0.f};
  f32x4 o[4];
#pragma unroll
  for (int dt = 0; dt < 4; ++dt) o[dt] = zero;
  float m_run[4], l_run[4];
#pragma unroll
  for (int r = 0; r < 4; ++r) { m_run[r] = -3.0e38f; l_run[r] = 0.f; }

  for (int kv0 = 0; kv0 < 2048; kv0 += 64) {
    f32x4 sc[4];
#pragma unroll
    for (int nt = 0; nt < 4; ++nt) sc[nt] = zero;
#pragma unroll
    for (int nt = 0; nt < 4; ++nt) {
      const __bf16* kr = kbase + (size_t)(kv0 + nt * 16 + l16) * 512;
      bf16x8 b0 = *(const bf16x8*)&kr[lg * 8];
      bf16x8 b1 = *(const bf16x8*)&kr[32 + lg * 8];
      sc[nt] = mfma16(qf0, b0, sc[nt]);
      sc[nt] = mfma16(qf1, b1, sc[nt]);
    }
    float mnew[4], alpha[4], rsum[4];
#pragma unroll
    for (int r = 0; r < 4; ++r) {
      float v0 = fmaxf(fmaxf(sc[0][r], sc[1][r]), fmaxf(sc[2][r], sc[3][r]));
#pragma unroll
      for (int d = 1; d < 16; d <<= 1) v0 = fmaxf(v0, __shfl_xor(v0, d));
      v0 *= 0.125f;
      mnew[r] = fmaxf(m_run[r], v0);
      alpha[r] = __expf(m_run[r] - mnew[r]);
      rsum[r] = 0.f;
    }
#pragma unroll
    for (int nt = 0; nt < 4; ++nt)
#pragma unroll
      for (int r = 0; r < 4; ++r) {
        float p = __expf(sc[nt][r] * 0.125f - mnew[r]);
        rsum[r] += p;
        lp[w][lg * 4 + r][nt * 16 + l16] = (__bf16)p;
      }
#pragma unroll
    for (int r = 0; r < 4; ++r) {
#pragma unroll
      for (int d = 1; d < 16; d <<= 1) rsum[r] += __shfl_xor(rsum[r], d);
      l_run[r] = l_run[r] * alpha[r] + rsum[r];
      m_run[r] = mnew[r];
      o[0][r] *= alpha[r]; o[1][r] *= alpha[r]; o[2][r] *= alpha[r]; o[3][r] *= alpha[r];
    }
    bf16x8 pa0 = *(const bf16x8*)&lp[w][l16][lg * 8];
    bf16x8 pa1 = *(const bf16x8*)&lp[w][l16][32 + lg * 8];
#pragma unroll
    for (int dt = 0; dt < 4; ++dt) {
      const __bf16* vr = vtb + (size_t)(dt * 16 + l16) * 2048 + kv0;
      bf16x8 v0 = *(const bf16x8*)&vr[lg * 8];
      bf16x8 v1 = *(const bf16x8*)&vr[32 + lg * 8];
      o[dt] = mfma16(pa0, v0, o[dt]);
      o[dt] = mfma16(pa1, v1, o[dt]);
    }
  }
  float inv[4];
#pragma unroll
  for (int r = 0; r < 4; ++r) inv[r] = 1.0f / l_run[r];
#pragma unroll
  for (int dt = 0; dt < 4; ++dt)
#pragma unroll
    for (int r = 0; r < 4; ++r)
      ao[(size_t)((b << 11) + s0 + lg * 4 + r) * 512 + hh * 64 + dt * 16 + l16] =
          (__bf16)(o[dt][r] * inv[r]);
}

// ---------------- out projection + residual + transpose to [B,C,S] ----------------
__global__ __launch_bounds__(256) void gemm_proj(const __bf16* __restrict__ A, const __bf16* __restrict__ W,
                                                 const float* __restrict__ bias,
                                                 const float* __restrict__ resid,
                                                 float* __restrict__ outp) {
  __shared__ __align__(16) union UU {
    struct SS { __bf16 a[128 * 64]; __bf16 b[128 * 64]; } s;
    float st[128 * 129];
  } u;
  int tid = threadIdx.x, wid = tid >> 6, l = tid & 63;
  int m0 = blockIdx.x * 128, n0 = blockIdx.y * 128;
  int wm = (wid >> 1) * 64, wn = (wid & 1) * 64;
  int l16 = l & 15, lg = l >> 4;
  f32x4 zero = {0.f, 0.f, 0.f, 0.f};
  f32x4 acc[4][4];
#pragma unroll
  for (int mt = 0; mt < 4; ++mt)
#pragma unroll
    for (int nt = 0; nt < 4; ++nt) acc[mt][nt] = zero;
  int srow = wid * 32 + (l >> 3);
  int scol = (l & 7) * 8;
  for (int k0 = 0; k0 < 512; k0 += 64) {
    __syncthreads();
#pragma unroll
    for (int t = 0; t < 4; ++t) {
      gload16(A + (size_t)(m0 + srow + t * 8) * 512 + k0 + scol, &u.s.a[(wid * 32 + t * 8) * 64]);
      gload16(W + (size_t)(n0 + srow + t * 8) * 512 + k0 + scol, &u.s.b[(wid * 32 + t * 8) * 64]);
    }
    __syncthreads();
#pragma unroll
    for (int kk = 0; kk < 64; kk += 32) {
      bf16x8 af[4], bfr[4];
#pragma unroll
      for (int mt = 0; mt < 4; ++mt) af[mt] = *(const bf16x8*)&u.s.a[(wm + mt * 16 + l16) * 64 + kk + lg * 8];
#pragma unroll
      for (int nt = 0; nt < 4; ++nt) bfr[nt] = *(const bf16x8*)&u.s.b[(wn + nt * 16 + l16) * 64 + kk + lg * 8];
#pragma unroll
      for (int mt = 0; mt < 4; ++mt)
#pragma unroll
        for (int nt = 0; nt < 4; ++nt) acc[mt][nt] = mfma16(af[mt], bfr[nt], acc[mt][nt]);
    }
  }
  __syncthreads();
#pragma unroll
  for (int nt = 0; nt < 4; ++nt) {
    int col = wn + nt * 16 + l16;
    float bb = bias[n0 + col];
#pragma unroll
    for (int mt = 0; mt < 4; ++mt)
#pragma unroll
      for (int r = 0; r < 4; ++r)
        u.st[(wm + mt * 16 + lg * 4 + r) * 129 + col] = acc[mt][nt][r] + bb;
  }
  __syncthreads();
  int b = m0 >> 11;
  int sbase = m0 & 2047;
  const float* rb = resid + ((size_t)b << 20);
  float* ob = outp + ((size_t)b << 20);
#pragma unroll
  for (int it = 0; it < 16; ++it) {
    int c = (tid >> 5) + it * 8;  // 0..127 local col
    int s4 = (tid & 31) * 4;      // 0..124 local row
    float4 r4 = *(const float4*)&rb[(size_t)(n0 + c) * 2048 + sbase + s4];
    float4 o4;
    o4.x = u.st[(s4 + 0) * 129 + c] + r4.x;
    o4.y = u.st[(s4 + 1) * 129 + c] + r4.y;
    o4.z = u.st[(s4 + 2) * 129 + c] + r4.z;
    o4.w = u.st[(s4 + 3) * 129 + c] + r4.w;
    *(float4*)&ob[(size_t)(n0 + c) * 2048 + sbase + s4] = o4;
  }
}

extern "C" void kernel_launch(void* const* d_in, const int* in_sizes, int n_in,
                              void* d_out, int out_size, void* d_ws, size_t ws_size,
                              hipStream_t stream) {
  const float* x   = (const float*)d_in[0];
  const float* gw  = (const float*)d_in[1];
  const float* gb  = (const float*)d_in[2];
  const float* wqf = (const float*)d_in[3];
  const float* bqf = (const float*)d_in[4];
  const float* wkf = (const float*)d_in[5];
  const float* bkf = (const float*)d_in[6];
  const float* wvf = (const float*)d_in[7];
  const float* bvf = (const float*)d_in[8];
  const float* wof = (const float*)d_in[9];
  const float* bof = (const float*)d_in[10];
  float* outp = (float*)d_out;

  char* ws = (char*)d_ws;
  float* stats = (float*)ws;
  const size_t MAT = (size_t)8192 * 512;  // elements
  __bf16* h  = (__bf16*)(ws + 256);
  __bf16* q  = h + MAT;
  __bf16* k  = q + MAT;
  __bf16* v  = k + MAT;
  __bf16* vt = v + MAT;
  __bf16* ao = vt + MAT;
  __bf16* wB = ao + MAT;  // 4 x 512*512

  hipMemsetAsync(stats, 0, 256, stream);
  gn_partial<<<dim3(64, 4), 256, 0, stream>>>(x, stats);
  gn_final<<<1, 64, 0, stream>>>(stats);
  norm_tr<<<dim3(32, 8, 4), 256, 0, stream>>>(x, gw, gb, stats, h);
  wcvt<<<1024, 256, 0, stream>>>(wqf, wkf, wvf, wof, wB);
  gemm_qkv<<<dim3(64, 4, 3), 256, 0, stream>>>(h, wB, bqf, bkf, bvf, q, k, v);
  v_tr<<<dim3(32, 8, 4), 256, 0, stream>>>(v, vt);
  attn<<<dim3(32, 8, 4), 256, 0, stream>>>(q, k, vt, ao);
  gemm_proj<<<dim3(64, 4), 256, 0, stream>>>(ao, wB + 3 * 262144, bof, x, outp);
}

// Round 2
// 279.646 us; speedup vs baseline: 1.3752x; 1.3752x over previous
//
#include <hip/hip_runtime.h>

typedef __attribute__((ext_vector_type(8))) __bf16 bf16x8;
typedef __attribute__((ext_vector_type(4))) __bf16 bf16x4;
typedef __attribute__((ext_vector_type(4))) float f32x4;

#define BSZ 4
#define CCH 512
#define SEQ 2048
#define NH  8
#define HD  64

__device__ __forceinline__ f32x4 mfma16(bf16x8 a, bf16x8 b, f32x4 c) {
  return __builtin_amdgcn_mfma_f32_16x16x32_bf16(a, b, c, 0, 0, 0);
}

__device__ __forceinline__ void gload16(const void* g, void* l) {
  __builtin_amdgcn_global_load_lds((const __attribute__((address_space(1))) void*)g,
                                   (__attribute__((address_space(3))) void*)l,
                                   16, 0, 0);
}

// ---------------- GroupNorm reduction ----------------
__global__ __launch_bounds__(256) void gn_partial(const float* __restrict__ x,
                                                  float* __restrict__ stats) {
  int b = blockIdx.y;
  const float4* xb = (const float4*)(x + ((size_t)b << 20) + (size_t)blockIdx.x * 16384);
  int tid = threadIdx.x;
  float s = 0.f, sq = 0.f;
#pragma unroll
  for (int i = 0; i < 16; ++i) {
    float4 v = xb[i * 256 + tid];
    s  += v.x + v.y + v.z + v.w;
    sq += v.x * v.x + v.y * v.y + v.z * v.z + v.w * v.w;
  }
#pragma unroll
  for (int o = 32; o > 0; o >>= 1) { s += __shfl_down(s, o); sq += __shfl_down(sq, o); }
  __shared__ float ls[4], lq[4];
  int w = tid >> 6;
  if ((tid & 63) == 0) { ls[w] = s; lq[w] = sq; }
  __syncthreads();
  if (tid == 0) {
    float S = ls[0] + ls[1] + ls[2] + ls[3];
    float Q = lq[0] + lq[1] + lq[2] + lq[3];
    atomicAdd(&stats[b], S);
    atomicAdd(&stats[4 + b], Q);
  }
}

__global__ void gn_final(float* stats) {
  int t = threadIdx.x;
  if (t < 4) {
    const float n = 1048576.f;
    float mean = stats[t] / n;
    float var = stats[4 + t] / n - mean * mean;
    stats[8 + t]  = mean;
    stats[12 + t] = rsqrtf(var + 1e-5f);
  }
}

// ---------------- normalize + transpose to [B*S, C] bf16 ----------------
__global__ __launch_bounds__(256) void norm_tr(const float* __restrict__ x,
                                               const float* __restrict__ gw,
                                               const float* __restrict__ gb,
                                               const float* __restrict__ stats,
                                               __bf16* __restrict__ h) {
  int s0 = blockIdx.x * 64, c0 = blockIdx.y * 64, b = blockIdx.z;
  float mean = stats[8 + b], rstd = stats[12 + b];
  const float* xb = x + ((size_t)b << 20);
  __shared__ __align__(16) __bf16 tile[64][72];
  int tid = threadIdx.x;
#pragma unroll
  for (int j = 0; j < 16; ++j) {
    int e = tid + j * 256;
    int cl = e >> 6, sl = e & 63;
    float vv = xb[(size_t)(c0 + cl) * 2048 + s0 + sl];
    float hn = (vv - mean) * rstd * gw[c0 + cl] + gb[c0 + cl];
    tile[cl][sl] = (__bf16)hn;
  }
  __syncthreads();
#pragma unroll
  for (int j = 0; j < 2; ++j) {
    int row = (tid >> 3) + j * 32;  // s-local
    int cg = tid & 7;
    bf16x8 pk;
#pragma unroll
    for (int e = 0; e < 8; ++e) pk[e] = tile[cg * 8 + e][row];
    *(bf16x8*)&h[(size_t)((b << 11) + s0 + row) * 512 + c0 + cg * 8] = pk;
  }
}

// ---------------- weights fp32 -> bf16 ----------------
__global__ __launch_bounds__(256) void wcvt(const float* __restrict__ wq, const float* __restrict__ wk,
                                            const float* __restrict__ wv, const float* __restrict__ wo,
                                            __bf16* __restrict__ out) {
  int i = blockIdx.x * 256 + threadIdx.x;  // 0..262143
  out[i]          = (__bf16)wq[i];
  out[262144 + i] = (__bf16)wk[i];
  out[524288 + i] = (__bf16)wv[i];
  out[786432 + i] = (__bf16)wo[i];
}

// ---------------- QKV GEMM: [8192,512] x [512,512]^T ----------------
__global__ __launch_bounds__(256) void gemm_qkv(const __bf16* __restrict__ A, const __bf16* __restrict__ Wb,
                                                const float* __restrict__ bq, const float* __restrict__ bk,
                                                const float* __restrict__ bvv,
                                                __bf16* __restrict__ oq, __bf16* __restrict__ ok,
                                                __bf16* __restrict__ ov) {
  __shared__ __align__(16) __bf16 As[128 * 64];
  __shared__ __align__(16) __bf16 Bs[128 * 64];
  int z = blockIdx.z;
  const __bf16* W = Wb + (size_t)z * 262144;
  const float* bias = z == 0 ? bq : (z == 1 ? bk : bvv);
  __bf16* out = z == 0 ? oq : (z == 1 ? ok : ov);
  int tid = threadIdx.x, wid = tid >> 6, l = tid & 63;
  int m0 = blockIdx.x * 128, n0 = blockIdx.y * 128;
  int wm = (wid >> 1) * 64, wn = (wid & 1) * 64;
  int l16 = l & 15, lg = l >> 4;
  f32x4 zero = {0.f, 0.f, 0.f, 0.f};
  f32x4 acc[4][4];
#pragma unroll
  for (int mt = 0; mt < 4; ++mt)
#pragma unroll
    for (int nt = 0; nt < 4; ++nt) acc[mt][nt] = zero;
  int srow = wid * 32 + (l >> 3);
  int scol = (l & 7) * 8;
  for (int k0 = 0; k0 < 512; k0 += 64) {
    __syncthreads();
#pragma unroll
    for (int t = 0; t < 4; ++t) {
      gload16(A + (size_t)(m0 + srow + t * 8) * 512 + k0 + scol, &As[(wid * 32 + t * 8) * 64]);
      gload16(W + (size_t)(n0 + srow + t * 8) * 512 + k0 + scol, &Bs[(wid * 32 + t * 8) * 64]);
    }
    __syncthreads();
#pragma unroll
    for (int kk = 0; kk < 64; kk += 32) {
      bf16x8 af[4], bfr[4];
#pragma unroll
      for (int mt = 0; mt < 4; ++mt) af[mt] = *(const bf16x8*)&As[(wm + mt * 16 + l16) * 64 + kk + lg * 8];
#pragma unroll
      for (int nt = 0; nt < 4; ++nt) bfr[nt] = *(const bf16x8*)&Bs[(wn + nt * 16 + l16) * 64 + kk + lg * 8];
#pragma unroll
      for (int mt = 0; mt < 4; ++mt)
#pragma unroll
        for (int nt = 0; nt < 4; ++nt) acc[mt][nt] = mfma16(af[mt], bfr[nt], acc[mt][nt]);
    }
  }
#pragma unroll
  for (int nt = 0; nt < 4; ++nt) {
    int col = n0 + wn + nt * 16 + l16;
    float bb = bias[col];
#pragma unroll
    for (int mt = 0; mt < 4; ++mt)
#pragma unroll
      for (int r = 0; r < 4; ++r)
        out[(size_t)(m0 + wm + mt * 16 + lg * 4 + r) * 512 + col] = (__bf16)(acc[mt][nt][r] + bb);
  }
}

// ---------------- V transpose -> V^T [B,H,D,S] ----------------
__global__ __launch_bounds__(256) void v_tr(const __bf16* __restrict__ v, __bf16* __restrict__ vt) {
  int s0 = blockIdx.x * 64, hh = blockIdx.y, b = blockIdx.z;
  __shared__ __align__(16) __bf16 tile[64][72];  // [d][s]
  int tid = threadIdx.x;
#pragma unroll
  for (int j = 0; j < 16; ++j) {
    int e = tid + j * 256;  // 0..4095
    int sl = e >> 6, dl = e & 63;
    tile[dl][sl] = v[(size_t)((b << 11) + s0 + sl) * 512 + hh * 64 + dl];
  }
  __syncthreads();
  const size_t base = (size_t)((b * 8 + hh) * 64) * 2048;
#pragma unroll
  for (int j = 0; j < 2; ++j) {
    int d = tid >> 2;             // 0..63
    int ch = (tid & 3) + j * 4;   // 0..7
    bf16x8 pk = *(const bf16x8*)&tile[d][ch * 8];
    *(bf16x8*)&vt[base + (size_t)d * 2048 + s0 + ch * 8] = pk;
  }
}

// ---------------- flash attention (swapped QK^T, 32 q-rows/wave) ----------------
// Per wave: 32 q-rows (two 16-row halves), KV tile = 64.
// QK: mfma(A=K-frag, B=Q-frag) -> sc[nt][h]: S[k = kv0+nt*16+lg*4+r][q = q0+16h+l16]
//   => softmax reduce over k is 15 in-lane fmax + 2 shfl_xor.
// P staged in XOR-swizzled LDS [32 q][64 k] per wave; PV: mfma(A=P-frag, B=Vt-frag).
__global__ __launch_bounds__(256) void attn(const __bf16* __restrict__ q, const __bf16* __restrict__ k,
                                            const __bf16* __restrict__ vt, __bf16* __restrict__ ao) {
  const float C2 = 0.18033688011f;  // (1/8) * log2(e)
  int tid = threadIdx.x, w = tid >> 6, l = tid & 63;
  int q0 = blockIdx.x * 128 + w * 32;  // wave's q-row base within batch
  int hh = blockIdx.y, b = blockIdx.z;
  int l16 = l & 15, lg = l >> 4;
  int swz = (l16 & 7) * 8;  // per-lane element-XOR for its LDS row

  // Q as B-fragment: row(l16) = q-row, k = lg*8
  bf16x8 qf[2][2];
#pragma unroll
  for (int h = 0; h < 2; ++h) {
    const __bf16* qrow = q + ((size_t)((b << 11) + q0 + h * 16 + l16)) * 512 + hh * 64;
    qf[h][0] = *(const bf16x8*)&qrow[lg * 8];
    qf[h][1] = *(const bf16x8*)&qrow[32 + lg * 8];
  }

  const __bf16* kbase = k + ((size_t)(b << 11)) * 512 + hh * 64;
  const __bf16* vtb = vt + ((size_t)((b * 8 + hh) * 64)) * 2048;

  __shared__ __align__(16) __bf16 lp[4][32 * 64];
  __bf16* plds = lp[w];

  f32x4 zero = {0.f, 0.f, 0.f, 0.f};
  f32x4 o[4][2];
#pragma unroll
  for (int dt = 0; dt < 4; ++dt)
#pragma unroll
    for (int h = 0; h < 2; ++h) o[dt][h] = zero;
  float m_run[2] = {-3.0e38f, -3.0e38f};
  float l_run[2] = {0.f, 0.f};

  for (int kv0 = 0; kv0 < 2048; kv0 += 64) {
    // K as A-fragment: row(l16) = k-row local
    bf16x8 kfr[4][2];
#pragma unroll
    for (int nt = 0; nt < 4; ++nt) {
      const __bf16* kr = kbase + (size_t)(kv0 + nt * 16 + l16) * 512;
      kfr[nt][0] = *(const bf16x8*)&kr[lg * 8];
      kfr[nt][1] = *(const bf16x8*)&kr[32 + lg * 8];
    }
    // V^T loads issued early (independent of softmax)
    bf16x8 vfr[4][2];
#pragma unroll
    for (int dt = 0; dt < 4; ++dt) {
      const __bf16* vr = vtb + (size_t)(dt * 16 + l16) * 2048 + kv0;
      vfr[dt][0] = *(const bf16x8*)&vr[lg * 8];
      vfr[dt][1] = *(const bf16x8*)&vr[32 + lg * 8];
    }

    f32x4 sc[4][2];
#pragma unroll
    for (int nt = 0; nt < 4; ++nt)
#pragma unroll
      for (int h = 0; h < 2; ++h) sc[nt][h] = zero;
#pragma unroll
    for (int nt = 0; nt < 4; ++nt)
#pragma unroll
      for (int h = 0; h < 2; ++h) {
        sc[nt][h] = mfma16(kfr[nt][0], qf[h][0], sc[nt][h]);
        sc[nt][h] = mfma16(kfr[nt][1], qf[h][1], sc[nt][h]);
      }

#pragma unroll
    for (int h = 0; h < 2; ++h) {
      // in-lane max over 16 values
      f32x4 mab;
#pragma unroll
      for (int c = 0; c < 4; ++c)
        mab[c] = fmaxf(fmaxf(sc[0][h][c], sc[1][h][c]), fmaxf(sc[2][h][c], sc[3][h][c]));
      float vmx = fmaxf(fmaxf(mab[0], mab[1]), fmaxf(mab[2], mab[3]));
      vmx = fmaxf(vmx, __shfl_xor(vmx, 16));
      vmx = fmaxf(vmx, __shfl_xor(vmx, 32));
      float mnew = fmaxf(m_run[h], vmx * C2);
      float alpha = exp2f(m_run[h] - mnew);
      m_run[h] = mnew;
      float rs = 0.f;
      int qrow = l16 + 16 * h;
#pragma unroll
      for (int nt = 0; nt < 4; ++nt) {
        bf16x4 pk4;
#pragma unroll
        for (int r = 0; r < 4; ++r) {
          float p = exp2f(sc[nt][h][r] * C2 - mnew);
          rs += p;
          pk4[r] = (__bf16)p;
        }
        *(bf16x4*)&plds[qrow * 64 + ((nt * 16 + lg * 4) ^ swz)] = pk4;
      }
      rs += __shfl_xor(rs, 16);
      rs += __shfl_xor(rs, 32);
      l_run[h] = l_run[h] * alpha + rs;
      // rescale o: alpha for o-row (lg*4+r) lives at lane (lg*4+r)
      float ar[4];
#pragma unroll
      for (int r = 0; r < 4; ++r) ar[r] = __shfl(alpha, lg * 4 + r);
#pragma unroll
      for (int dt = 0; dt < 4; ++dt)
#pragma unroll
        for (int r = 0; r < 4; ++r) o[dt][h][r] *= ar[r];
    }

    // PV: A = P rows (q), B = Vt rows (d)
#pragma unroll
    for (int h = 0; h < 2; ++h) {
      int qrow = l16 + 16 * h;
      bf16x8 pa0 = *(const bf16x8*)&plds[qrow * 64 + ((lg * 8) ^ swz)];
      bf16x8 pa1 = *(const bf16x8*)&plds[qrow * 64 + ((32 + lg * 8) ^ swz)];
#pragma unroll
      for (int dt = 0; dt < 4; ++dt) {
        o[dt][h] = mfma16(pa0, vfr[dt][0], o[dt][h]);
        o[dt][h] = mfma16(pa1, vfr[dt][1], o[dt][h]);
      }
    }
  }

#pragma unroll
  for (int h = 0; h < 2; ++h) {
    float invl = 1.0f / l_run[h];
    float ir[4];
#pragma unroll
    for (int r = 0; r < 4; ++r) ir[r] = __shfl(invl, lg * 4 + r);
#pragma unroll
    for (int dt = 0; dt < 4; ++dt)
#pragma unroll
      for (int r = 0; r < 4; ++r)
        ao[(size_t)((b << 11) + q0 + 16 * h + lg * 4 + r) * 512 + hh * 64 + dt * 16 + l16] =
            (__bf16)(o[dt][h][r] * ir[r]);
  }
}

// ---------------- out projection + residual + transpose to [B,C,S] ----------------
__global__ __launch_bounds__(256) void gemm_proj(const __bf16* __restrict__ A, const __bf16* __restrict__ W,
                                                 const float* __restrict__ bias,
                                                 const float* __restrict__ resid,
                                                 float* __restrict__ outp) {
  __shared__ __align__(16) union UU {
    struct SS { __bf16 a[128 * 64]; __bf16 b[128 * 64]; } s;
    float st[128 * 129];
  } u;
  int tid = threadIdx.x, wid = tid >> 6, l = tid & 63;
  int m0 = blockIdx.x * 128, n0 = blockIdx.y * 128;
  int wm = (wid >> 1) * 64, wn = (wid & 1) * 64;
  int l16 = l & 15, lg = l >> 4;
  f32x4 zero = {0.f, 0.f, 0.f, 0.f};
  f32x4 acc[4][4];
#pragma unroll
  for (int mt = 0; mt < 4; ++mt)
#pragma unroll
    for (int nt = 0; nt < 4; ++nt) acc[mt][nt] = zero;
  int srow = wid * 32 + (l >> 3);
  int scol = (l & 7) * 8;
  for (int k0 = 0; k0 < 512; k0 += 64) {
    __syncthreads();
#pragma unroll
    for (int t = 0; t < 4; ++t) {
      gload16(A + (size_t)(m0 + srow + t * 8) * 512 + k0 + scol, &u.s.a[(wid * 32 + t * 8) * 64]);
      gload16(W + (size_t)(n0 + srow + t * 8) * 512 + k0 + scol, &u.s.b[(wid * 32 + t * 8) * 64]);
    }
    __syncthreads();
#pragma unroll
    for (int kk = 0; kk < 64; kk += 32) {
      bf16x8 af[4], bfr[4];
#pragma unroll
      for (int mt = 0; mt < 4; ++mt) af[mt] = *(const bf16x8*)&u.s.a[(wm + mt * 16 + l16) * 64 + kk + lg * 8];
#pragma unroll
      for (int nt = 0; nt < 4; ++nt) bfr[nt] = *(const bf16x8*)&u.s.b[(wn + nt * 16 + l16) * 64 + kk + lg * 8];
#pragma unroll
      for (int mt = 0; mt < 4; ++mt)
#pragma unroll
        for (int nt = 0; nt < 4; ++nt) acc[mt][nt] = mfma16(af[mt], bfr[nt], acc[mt][nt]);
    }
  }
  __syncthreads();
#pragma unroll
  for (int nt = 0; nt < 4; ++nt) {
    int col = wn + nt * 16 + l16;
    float bb = bias[n0 + col];
#pragma unroll
    for (int mt = 0; mt < 4; ++mt)
#pragma unroll
      for (int r = 0; r < 4; ++r)
        u.st[(wm + mt * 16 + lg * 4 + r) * 129 + col] = acc[mt][nt][r] + bb;
  }
  __syncthreads();
  int b = m0 >> 11;
  int sbase = m0 & 2047;
  const float* rb = resid + ((size_t)b << 20);
  float* ob = outp + ((size_t)b << 20);
#pragma unroll
  for (int it = 0; it < 16; ++it) {
    int c = (tid >> 5) + it * 8;  // 0..127 local col
    int s4 = (tid & 31) * 4;      // 0..124 local row
    float4 r4 = *(const float4*)&rb[(size_t)(n0 + c) * 2048 + sbase + s4];
    float4 o4;
    o4.x = u.st[(s4 + 0) * 129 + c] + r4.x;
    o4.y = u.st[(s4 + 1) * 129 + c] + r4.y;
    o4.z = u.st[(s4 + 2) * 129 + c] + r4.z;
    o4.w = u.st[(s4 + 3) * 129 + c] + r4.w;
    *(float4*)&ob[(size_t)(n0 + c) * 2048 + sbase + s4] = o4;
  }
}

extern "C" void kernel_launch(void* const* d_in, const int* in_sizes, int n_in,
                              void* d_out, int out_size, void* d_ws, size_t ws_size,
                              hipStream_t stream) {
  const float* x   = (const float*)d_in[0];
  const float* gw  = (const float*)d_in[1];
  const float* gb  = (const float*)d_in[2];
  const float* wqf = (const float*)d_in[3];
  const float* bqf = (const float*)d_in[4];
  const float* wkf = (const float*)d_in[5];
  const float* bkf = (const float*)d_in[6];
  const float* wvf = (const float*)d_in[7];
  const float* bvf = (const float*)d_in[8];
  const float* wof = (const float*)d_in[9];
  const float* bof = (const float*)d_in[10];
  float* outp = (float*)d_out;

  char* ws = (char*)d_ws;
  float* stats = (float*)ws;
  const size_t MAT = (size_t)8192 * 512;  // elements
  __bf16* h  = (__bf16*)(ws + 256);
  __bf16* q  = h + MAT;
  __bf16* k  = q + MAT;
  __bf16* v  = k + MAT;
  __bf16* vt = v + MAT;
  __bf16* ao = vt + MAT;
  __bf16* wB = ao + MAT;  // 4 x 512*512

  hipMemsetAsync(stats, 0, 256, stream);
  gn_partial<<<dim3(64, 4), 256, 0, stream>>>(x, stats);
  gn_final<<<1, 64, 0, stream>>>(stats);
  norm_tr<<<dim3(32, 8, 4), 256, 0, stream>>>(x, gw, gb, stats, h);
  wcvt<<<1024, 256, 0, stream>>>(wqf, wkf, wvf, wof, wB);
  gemm_qkv<<<dim3(64, 4, 3), 256, 0, stream>>>(h, wB, bqf, bkf, bvf, q, k, v);
  v_tr<<<dim3(32, 8, 4), 256, 0, stream>>>(v, vt);
  attn<<<dim3(16, 8, 4), 256, 0, stream>>>(q, k, vt, ao);
  gemm_proj<<<dim3(64, 4), 256, 0, stream>>>(ao, wB + 3 * 262144, bof, x, outp);
}

// Round 3
// 277.106 us; speedup vs baseline: 1.3878x; 1.0092x over previous
//
#include <hip/hip_runtime.h>

typedef __attribute__((ext_vector_type(8))) __bf16 bf16x8;
typedef __attribute__((ext_vector_type(4))) __bf16 bf16x4;
typedef __attribute__((ext_vector_type(4))) float f32x4;
typedef __attribute__((ext_vector_type(16))) float f32x16;

#define BSZ 4
#define CCH 512
#define SEQ 2048
#define NH  8
#define HD  64

__device__ __forceinline__ f32x4 mfma16(bf16x8 a, bf16x8 b, f32x4 c) {
  return __builtin_amdgcn_mfma_f32_16x16x32_bf16(a, b, c, 0, 0, 0);
}
__device__ __forceinline__ f32x16 mfma32(bf16x8 a, bf16x8 b, f32x16 c) {
  return __builtin_amdgcn_mfma_f32_32x32x16_bf16(a, b, c, 0, 0, 0);
}

__device__ __forceinline__ void gload16(const void* g, void* l) {
  __builtin_amdgcn_global_load_lds((const __attribute__((address_space(1))) void*)g,
                                   (__attribute__((address_space(3))) void*)l,
                                   16, 0, 0);
}

__device__ __forceinline__ unsigned cvtpk(float lo, float hi) {
  unsigned r;
  asm("v_cvt_pk_bf16_f32 %0, %1, %2" : "=v"(r) : "v"(lo), "v"(hi));
  return r;
}
__device__ __forceinline__ void pl32swap(unsigned& a, unsigned& b) {
  asm("v_permlane32_swap_b32 %0, %1" : "+v"(a), "+v"(b));
}

// ---------------- GroupNorm reduction ----------------
__global__ __launch_bounds__(256) void gn_partial(const float* __restrict__ x,
                                                  float* __restrict__ stats) {
  int b = blockIdx.y;
  const float4* xb = (const float4*)(x + ((size_t)b << 20) + (size_t)blockIdx.x * 16384);
  int tid = threadIdx.x;
  float s = 0.f, sq = 0.f;
#pragma unroll
  for (int i = 0; i < 16; ++i) {
    float4 v = xb[i * 256 + tid];
    s  += v.x + v.y + v.z + v.w;
    sq += v.x * v.x + v.y * v.y + v.z * v.z + v.w * v.w;
  }
#pragma unroll
  for (int o = 32; o > 0; o >>= 1) { s += __shfl_down(s, o); sq += __shfl_down(sq, o); }
  __shared__ float ls[4], lq[4];
  int w = tid >> 6;
  if ((tid & 63) == 0) { ls[w] = s; lq[w] = sq; }
  __syncthreads();
  if (tid == 0) {
    float S = ls[0] + ls[1] + ls[2] + ls[3];
    float Q = lq[0] + lq[1] + lq[2] + lq[3];
    atomicAdd(&stats[b], S);
    atomicAdd(&stats[4 + b], Q);
  }
}

__global__ void gn_final(float* stats) {
  int t = threadIdx.x;
  if (t < 4) {
    const float n = 1048576.f;
    float mean = stats[t] / n;
    float var = stats[4 + t] / n - mean * mean;
    stats[8 + t]  = mean;
    stats[12 + t] = rsqrtf(var + 1e-5f);
  }
}

// ---------------- normalize + transpose to [B*S, C] bf16 ----------------
__global__ __launch_bounds__(256) void norm_tr(const float* __restrict__ x,
                                               const float* __restrict__ gw,
                                               const float* __restrict__ gb,
                                               const float* __restrict__ stats,
                                               __bf16* __restrict__ h) {
  int s0 = blockIdx.x * 64, c0 = blockIdx.y * 64, b = blockIdx.z;
  float mean = stats[8 + b], rstd = stats[12 + b];
  const float* xb = x + ((size_t)b << 20);
  __shared__ __align__(16) __bf16 tile[64][72];
  int tid = threadIdx.x;
#pragma unroll
  for (int j = 0; j < 16; ++j) {
    int e = tid + j * 256;
    int cl = e >> 6, sl = e & 63;
    float vv = xb[(size_t)(c0 + cl) * 2048 + s0 + sl];
    float hn = (vv - mean) * rstd * gw[c0 + cl] + gb[c0 + cl];
    tile[cl][sl] = (__bf16)hn;
  }
  __syncthreads();
#pragma unroll
  for (int j = 0; j < 2; ++j) {
    int row = (tid >> 3) + j * 32;  // s-local
    int cg = tid & 7;
    bf16x8 pk;
#pragma unroll
    for (int e = 0; e < 8; ++e) pk[e] = tile[cg * 8 + e][row];
    *(bf16x8*)&h[(size_t)((b << 11) + s0 + row) * 512 + c0 + cg * 8] = pk;
  }
}

// ---------------- weights fp32 -> bf16 ----------------
__global__ __launch_bounds__(256) void wcvt(const float* __restrict__ wq, const float* __restrict__ wk,
                                            const float* __restrict__ wv, const float* __restrict__ wo,
                                            __bf16* __restrict__ out) {
  int i = blockIdx.x * 256 + threadIdx.x;  // 0..262143
  out[i]          = (__bf16)wq[i];
  out[262144 + i] = (__bf16)wk[i];
  out[524288 + i] = (__bf16)wv[i];
  out[786432 + i] = (__bf16)wo[i];
}

// ---------------- QKV GEMM: [8192,512] x [512,512]^T ----------------
__global__ __launch_bounds__(256) void gemm_qkv(const __bf16* __restrict__ A, const __bf16* __restrict__ Wb,
                                                const float* __restrict__ bq, const float* __restrict__ bk,
                                                const float* __restrict__ bvv,
                                                __bf16* __restrict__ oq, __bf16* __restrict__ ok,
                                                __bf16* __restrict__ ov) {
  __shared__ __align__(16) __bf16 As[128 * 64];
  __shared__ __align__(16) __bf16 Bs[128 * 64];
  int z = blockIdx.z;
  const __bf16* W = Wb + (size_t)z * 262144;
  const float* bias = z == 0 ? bq : (z == 1 ? bk : bvv);
  __bf16* out = z == 0 ? oq : (z == 1 ? ok : ov);
  int tid = threadIdx.x, wid = tid >> 6, l = tid & 63;
  int m0 = blockIdx.x * 128, n0 = blockIdx.y * 128;
  int wm = (wid >> 1) * 64, wn = (wid & 1) * 64;
  int l16 = l & 15, lg = l >> 4;
  f32x4 zero = {0.f, 0.f, 0.f, 0.f};
  f32x4 acc[4][4];
#pragma unroll
  for (int mt = 0; mt < 4; ++mt)
#pragma unroll
    for (int nt = 0; nt < 4; ++nt) acc[mt][nt] = zero;
  int srow = wid * 32 + (l >> 3);
  int scol = (l & 7) * 8;
  for (int k0 = 0; k0 < 512; k0 += 64) {
    __syncthreads();
#pragma unroll
    for (int t = 0; t < 4; ++t) {
      gload16(A + (size_t)(m0 + srow + t * 8) * 512 + k0 + scol, &As[(wid * 32 + t * 8) * 64]);
      gload16(W + (size_t)(n0 + srow + t * 8) * 512 + k0 + scol, &Bs[(wid * 32 + t * 8) * 64]);
    }
    __syncthreads();
#pragma unroll
    for (int kk = 0; kk < 64; kk += 32) {
      bf16x8 af[4], bfr[4];
#pragma unroll
      for (int mt = 0; mt < 4; ++mt) af[mt] = *(const bf16x8*)&As[(wm + mt * 16 + l16) * 64 + kk + lg * 8];
#pragma unroll
      for (int nt = 0; nt < 4; ++nt) bfr[nt] = *(const bf16x8*)&Bs[(wn + nt * 16 + l16) * 64 + kk + lg * 8];
#pragma unroll
      for (int mt = 0; mt < 4; ++mt)
#pragma unroll
        for (int nt = 0; nt < 4; ++nt) acc[mt][nt] = mfma16(af[mt], bfr[nt], acc[mt][nt]);
    }
  }
#pragma unroll
  for (int nt = 0; nt < 4; ++nt) {
    int col = n0 + wn + nt * 16 + l16;
    float bb = bias[col];
#pragma unroll
    for (int mt = 0; mt < 4; ++mt)
#pragma unroll
      for (int r = 0; r < 4; ++r)
        out[(size_t)(m0 + wm + mt * 16 + lg * 4 + r) * 512 + col] = (__bf16)(acc[mt][nt][r] + bb);
  }
}

// ---------------- V transpose -> V^T [B,H,D,S] ----------------
__global__ __launch_bounds__(256) void v_tr(const __bf16* __restrict__ v, __bf16* __restrict__ vt) {
  int s0 = blockIdx.x * 64, hh = blockIdx.y, b = blockIdx.z;
  __shared__ __align__(16) __bf16 tile[64][72];  // [d][s]
  int tid = threadIdx.x;
#pragma unroll
  for (int j = 0; j < 16; ++j) {
    int e = tid + j * 256;  // 0..4095
    int sl = e >> 6, dl = e & 63;
    tile[dl][sl] = v[(size_t)((b << 11) + s0 + sl) * 512 + hh * 64 + dl];
  }
  __syncthreads();
  const size_t base = (size_t)((b * 8 + hh) * 64) * 2048;
#pragma unroll
  for (int j = 0; j < 2; ++j) {
    int d = tid >> 2;             // 0..63
    int ch = (tid & 3) + j * 4;   // 0..7
    bf16x8 pk = *(const bf16x8*)&tile[d][ch * 8];
    *(bf16x8*)&vt[base + (size_t)d * 2048 + s0 + ch * 8] = pk;
  }
}

// ---------------- flash attention: 32x32 MFMA, in-register P ----------------
// Wave: 32 q-rows. KV step 32.
// QK: mfma32(A=K-frag, B=Q-frag) -> sc: S[k=(r&3)+8*(r>>2)+4*hi][q=lane&31]
// softmax per-lane (q = lane&31): in-lane 16-max/sum + 1 cross-hi shfl_xor(32).
// P -> PV B-frag: cvt_pk_bf16 pairs + permlane32_swap (no LDS).
// PV: mfma32(A=Vt-frag, B=P-frag) -> O^T[d][q], same lane-q as softmax state.
__global__ __launch_bounds__(256) void attn(const __bf16* __restrict__ q, const __bf16* __restrict__ k,
                                            const __bf16* __restrict__ vt, __bf16* __restrict__ ao) {
  const float C2 = 0.18033688011f;  // (1/8) * log2(e)
  const float THR = 8.0f;           // defer-max threshold (log2 units)
  int tid = threadIdx.x, w = tid >> 6, l = tid & 63;
  int q0w = blockIdx.x * 128 + w * 32;  // wave's q-row base within batch
  int hh = blockIdx.y, b = blockIdx.z;
  int l31 = l & 31, hi = l >> 5;

  // Q B-frags: lane holds Q[q0w+l31][hh*64 + dt*16 + hi*8 + j]
  bf16x8 qf[4];
  {
    const __bf16* qrow = q + ((size_t)((b << 11) + q0w + l31)) * 512 + hh * 64 + hi * 8;
#pragma unroll
    for (int dt = 0; dt < 4; ++dt) qf[dt] = *(const bf16x8*)&qrow[dt * 16];
  }

  const __bf16* kbase = k + ((size_t)(b << 11)) * 512 + hh * 64 + hi * 8;
  const __bf16* vtb = vt + ((size_t)((b * 8 + hh) * 64)) * 2048;

  f32x16 zero16 = {};
  f32x16 o2[2];
  o2[0] = zero16; o2[1] = zero16;
  float m_run = -3.0e38f, l_run = 0.f;

#pragma unroll 2
  for (int kv0 = 0; kv0 < 2048; kv0 += 32) {
    // K A-frags: lane holds K[kv0+l31][hh*64 + dt*16 + hi*8 + j]
    const __bf16* kr = kbase + (size_t)(kv0 + l31) * 512;
    bf16x8 kfr[4];
#pragma unroll
    for (int dt = 0; dt < 4; ++dt) kfr[dt] = *(const bf16x8*)&kr[dt * 16];
    // V A-frags: lane holds Vt[dblk*32+l31][kv0 + t*16 + hi*8 + j]
    bf16x8 va[2][2];
#pragma unroll
    for (int dblk = 0; dblk < 2; ++dblk) {
      const __bf16* vr = vtb + (size_t)(dblk * 32 + l31) * 2048 + kv0 + hi * 8;
      va[dblk][0] = *(const bf16x8*)&vr[0];
      va[dblk][1] = *(const bf16x8*)&vr[16];
    }

    f32x16 sc = zero16;
#pragma unroll
    for (int dt = 0; dt < 4; ++dt) sc = mfma32(kfr[dt], qf[dt], sc);

    // --- softmax (per lane = per q-row) ---
    float t0 = fmaxf(fmaxf(sc[0], sc[1]), fmaxf(sc[2], sc[3]));
    float t1 = fmaxf(fmaxf(sc[4], sc[5]), fmaxf(sc[6], sc[7]));
    float t2 = fmaxf(fmaxf(sc[8], sc[9]), fmaxf(sc[10], sc[11]));
    float t3 = fmaxf(fmaxf(sc[12], sc[13]), fmaxf(sc[14], sc[15]));
    float tmax = fmaxf(fmaxf(t0, t1), fmaxf(t2, t3));
    tmax = fmaxf(tmax, __shfl_xor(tmax, 32));
    tmax *= C2;
    if (!__all(tmax <= m_run + THR)) {
      float mnew = fmaxf(m_run, tmax);
      float alpha = exp2f(m_run - mnew);
      m_run = mnew;
      l_run *= alpha;
#pragma unroll
      for (int dblk = 0; dblk < 2; ++dblk)
#pragma unroll
        for (int r = 0; r < 16; ++r) o2[dblk][r] *= alpha;
    }
    float rs = 0.f;
#pragma unroll
    for (int r = 0; r < 16; ++r) {
      float p = exp2f(__builtin_fmaf(sc[r], C2, -m_run));
      rs += p;
      sc[r] = p;
    }
    rs += __shfl_xor(rs, 32);
    l_run += rs;

    // --- P -> B-frags (in-register) ---
#pragma unroll
    for (int t = 0; t < 2; ++t) {
      unsigned u0 = cvtpk(sc[8 * t + 0], sc[8 * t + 1]);
      unsigned u1 = cvtpk(sc[8 * t + 2], sc[8 * t + 3]);
      unsigned u2 = cvtpk(sc[8 * t + 4], sc[8 * t + 5]);
      unsigned u3 = cvtpk(sc[8 * t + 6], sc[8 * t + 7]);
      pl32swap(u0, u2);
      pl32swap(u1, u3);
      union { unsigned u[4]; bf16x8 v; } pb;
      pb.u[0] = u0; pb.u[1] = u1; pb.u[2] = u2; pb.u[3] = u3;
#pragma unroll
      for (int dblk = 0; dblk < 2; ++dblk) o2[dblk] = mfma32(va[dblk][t], pb.v, o2[dblk]);
    }
  }

  // --- epilogue: normalize, transpose O^T->O via LDS, store ---
  float invl = 1.0f / l_run;
  __shared__ __align__(16) __bf16 tl[4][32 * 64];
  __bf16* T = tl[w];
  int swzq = (l31 & 7) * 8;
#pragma unroll
  for (int dblk = 0; dblk < 2; ++dblk)
#pragma unroll
    for (int g = 0; g < 4; ++g) {
      unsigned w0 = cvtpk(o2[dblk][g * 4 + 0] * invl, o2[dblk][g * 4 + 1] * invl);
      unsigned w1 = cvtpk(o2[dblk][g * 4 + 2] * invl, o2[dblk][g * 4 + 3] * invl);
      int d4 = dblk * 32 + g * 8 + hi * 4;
      uint2 pk2; pk2.x = w0; pk2.y = w1;
      *(uint2*)&T[l31 * 64 + (d4 ^ swzq)] = pk2;
    }
  // same-wave read-back (compiler inserts lgkmcnt wait)
  int qr = l >> 1, hf = l & 1;
  int swzr = (qr & 7) * 8;
  __bf16* aorow = ao + (size_t)((b << 11) + q0w + qr) * 512 + hh * 64;
#pragma unroll
  for (int m = 0; m < 2; ++m) {
    int e = hf * 32 + m * 16;
    bf16x8 v0 = *(const bf16x8*)&T[qr * 64 + ((e) ^ swzr)];
    bf16x8 v1 = *(const bf16x8*)&T[qr * 64 + ((e + 8) ^ swzr)];
    *(bf16x8*)&aorow[e] = v0;
    *(bf16x8*)&aorow[e + 8] = v1;
  }
}

// ---------------- out projection + residual + transpose to [B,C,S] ----------------
__global__ __launch_bounds__(256) void gemm_proj(const __bf16* __restrict__ A, const __bf16* __restrict__ W,
                                                 const float* __restrict__ bias,
                                                 const float* __restrict__ resid,
                                                 float* __restrict__ outp) {
  __shared__ __align__(16) union UU {
    struct SS { __bf16 a[128 * 64]; __bf16 b[128 * 64]; } s;
    float st[128 * 129];
  } u;
  int tid = threadIdx.x, wid = tid >> 6, l = tid & 63;
  int m0 = blockIdx.x * 128, n0 = blockIdx.y * 128;
  int wm = (wid >> 1) * 64, wn = (wid & 1) * 64;
  int l16 = l & 15, lg = l >> 4;
  f32x4 zero = {0.f, 0.f, 0.f, 0.f};
  f32x4 acc[4][4];
#pragma unroll
  for (int mt = 0; mt < 4; ++mt)
#pragma unroll
    for (int nt = 0; nt < 4; ++nt) acc[mt][nt] = zero;
  int srow = wid * 32 + (l >> 3);
  int scol = (l & 7) * 8;
  for (int k0 = 0; k0 < 512; k0 += 64) {
    __syncthreads();
#pragma unroll
    for (int t = 0; t < 4; ++t) {
      gload16(A + (size_t)(m0 + srow + t * 8) * 512 + k0 + scol, &u.s.a[(wid * 32 + t * 8) * 64]);
      gload16(W + (size_t)(n0 + srow + t * 8) * 512 + k0 + scol, &u.s.b[(wid * 32 + t * 8) * 64]);
    }
    __syncthreads();
#pragma unroll
    for (int kk = 0; kk < 64; kk += 32) {
      bf16x8 af[4], bfr[4];
#pragma unroll
      for (int mt = 0; mt < 4; ++mt) af[mt] = *(const bf16x8*)&u.s.a[(wm + mt * 16 + l16) * 64 + kk + lg * 8];
#pragma unroll
      for (int nt = 0; nt < 4; ++nt) bfr[nt] = *(const bf16x8*)&u.s.b[(wn + nt * 16 + l16) * 64 + kk + lg * 8];
#pragma unroll
      for (int mt = 0; mt < 4; ++mt)
#pragma unroll
        for (int nt = 0; nt < 4; ++nt) acc[mt][nt] = mfma16(af[mt], bfr[nt], acc[mt][nt]);
    }
  }
  __syncthreads();
#pragma unroll
  for (int nt = 0; nt < 4; ++nt) {
    int col = wn + nt * 16 + l16;
    float bb = bias[n0 + col];
#pragma unroll
    for (int mt = 0; mt < 4; ++mt)
#pragma unroll
      for (int r = 0; r < 4; ++r)
        u.st[(wm + mt * 16 + lg * 4 + r) * 129 + col] = acc[mt][nt][r] + bb;
  }
  __syncthreads();
  int b = m0 >> 11;
  int sbase = m0 & 2047;
  const float* rb = resid + ((size_t)b << 20);
  float* ob = outp + ((size_t)b << 20);
#pragma unroll
  for (int it = 0; it < 16; ++it) {
    int c = (tid >> 5) + it * 8;  // 0..127 local col
    int s4 = (tid & 31) * 4;      // 0..124 local row
    float4 r4 = *(const float4*)&rb[(size_t)(n0 + c) * 2048 + sbase + s4];
    float4 o4;
    o4.x = u.st[(s4 + 0) * 129 + c] + r4.x;
    o4.y = u.st[(s4 + 1) * 129 + c] + r4.y;
    o4.z = u.st[(s4 + 2) * 129 + c] + r4.z;
    o4.w = u.st[(s4 + 3) * 129 + c] + r4.w;
    *(float4*)&ob[(size_t)(n0 + c) * 2048 + sbase + s4] = o4;
  }
}

extern "C" void kernel_launch(void* const* d_in, const int* in_sizes, int n_in,
                              void* d_out, int out_size, void* d_ws, size_t ws_size,
                              hipStream_t stream) {
  const float* x   = (const float*)d_in[0];
  const float* gw  = (const float*)d_in[1];
  const float* gb  = (const float*)d_in[2];
  const float* wqf = (const float*)d_in[3];
  const float* bqf = (const float*)d_in[4];
  const float* wkf = (const float*)d_in[5];
  const float* bkf = (const float*)d_in[6];
  const float* wvf = (const float*)d_in[7];
  const float* bvf = (const float*)d_in[8];
  const float* wof = (const float*)d_in[9];
  const float* bof = (const float*)d_in[10];
  float* outp = (float*)d_out;

  char* ws = (char*)d_ws;
  float* stats = (float*)ws;
  const size_t MAT = (size_t)8192 * 512;  // elements
  __bf16* h  = (__bf16*)(ws + 256);
  __bf16* q  = h + MAT;
  __bf16* k  = q + MAT;
  __bf16* v  = k + MAT;
  __bf16* vt = v + MAT;
  __bf16* ao = vt + MAT;
  __bf16* wB = ao + MAT;  // 4 x 512*512

  hipMemsetAsync(stats, 0, 256, stream);
  gn_partial<<<dim3(64, 4), 256, 0, stream>>>(x, stats);
  gn_final<<<1, 64, 0, stream>>>(stats);
  norm_tr<<<dim3(32, 8, 4), 256, 0, stream>>>(x, gw, gb, stats, h);
  wcvt<<<1024, 256, 0, stream>>>(wqf, wkf, wvf, wof, wB);
  gemm_qkv<<<dim3(64, 4, 3), 256, 0, stream>>>(h, wB, bqf, bkf, bvf, q, k, v);
  v_tr<<<dim3(32, 8, 4), 256, 0, stream>>>(v, vt);
  attn<<<dim3(16, 8, 4), 256, 0, stream>>>(q, k, vt, ao);
  gemm_proj<<<dim3(64, 4), 256, 0, stream>>>(ao, wB + 3 * 262144, bof, x, outp);
}